// Round 7
// baseline (299.193 us; speedup 1.0000x reference)
//
#include <hip/hip_runtime.h>
#include <cstddef>

#define NN 20000
#define NE 320000

typedef short bf16x8 __attribute__((ext_vector_type(8)));
typedef float f32x4 __attribute__((ext_vector_type(4)));
typedef unsigned short u16;

__device__ __forceinline__ float bf2f(u16 u) {
    unsigned x = ((unsigned)u) << 16;
    return __builtin_bit_cast(float, x);
}
__device__ __forceinline__ u16 f2bf(float f) {
    unsigned x = __builtin_bit_cast(unsigned, f);
    x = (x + 0x7fff + ((x >> 16) & 1)) >> 16;   // round-to-nearest-even
    return (u16)x;
}

// ---------------- edge-index layout detection (low-contention) ----------------
__global__ __launch_bounds__(256) void detect_kernel(const void* __restrict__ edges, int* flag) {
    __shared__ int bad;
    if (threadIdx.x == 0) bad = 0;
    __syncthreads();
    int any = 0;
    for (int i = blockIdx.x * 256 + threadIdx.x; i < NE; i += 64 * 256) {
        long long v = ((const long long*)edges)[i];
        if (v < 0 || v >= NN) any = 1;
    }
    if (any) bad = 1;               // benign LDS race: all write 1
    __syncthreads();
    if (threadIdx.x == 0 && bad) atomicOr(flag, 1);
}

__global__ __launch_bounds__(256) void convert_kernel(const void* __restrict__ edges,
                                                      const int* __restrict__ flag,
                                                      int* __restrict__ src, int* __restrict__ dst,
                                                      int* __restrict__ deg) {
    int i = blockIdx.x * blockDim.x + threadIdx.x;
    if (i >= NE) return;
    int s, d;
    if (*flag) {
        s = ((const int*)edges)[i];
        d = ((const int*)edges)[NE + i];
    } else {
        s = (int)((const long long*)edges)[i];
        d = (int)((const long long*)edges)[NE + i];
    }
    src[i] = s;
    dst[i] = d;
    atomicAdd(&deg[d], 1);
}

// ---------------- parallel exclusive scan (3 phases) ----------------
__global__ __launch_bounds__(256) void scan1_kernel(const int* __restrict__ deg,
                                                    int* __restrict__ incl, int* __restrict__ bsum) {
    __shared__ int buf[256];
    int t = threadIdx.x, i = blockIdx.x * 256 + t;
    int v = (i < NN) ? deg[i] : 0;
    buf[t] = v;
    __syncthreads();
    for (int off = 1; off < 256; off <<= 1) {
        int u = (t >= off) ? buf[t - off] : 0;
        __syncthreads();
        buf[t] += u;
        __syncthreads();
    }
    if (i < NN) incl[i] = buf[t];
    if (t == 255) bsum[blockIdx.x] = buf[255];
}

__global__ __launch_bounds__(256) void scan2_kernel(const int* __restrict__ bsum,
                                                    int* __restrict__ boff) {
    __shared__ int buf[256];
    const int nb = (NN + 255) / 256;   // 79
    int t = threadIdx.x;
    int v = (t < nb) ? bsum[t] : 0;
    buf[t] = v;
    __syncthreads();
    for (int off = 1; off < 256; off <<= 1) {
        int u = (t >= off) ? buf[t - off] : 0;
        __syncthreads();
        buf[t] += u;
        __syncthreads();
    }
    if (t < nb) boff[t] = buf[t] - v;   // exclusive
}

__global__ __launch_bounds__(256) void scan3_kernel(const int* __restrict__ deg,
                                                    const int* __restrict__ incl,
                                                    const int* __restrict__ boff,
                                                    int* __restrict__ rowptr) {
    int i = blockIdx.x * 256 + threadIdx.x;
    if (i < NN) rowptr[i] = boff[i >> 8] + incl[i] - deg[i];
    if (i == NN) rowptr[NN] = NE;
}

// ---------------- CSR fill ----------------
__global__ __launch_bounds__(256) void fill_kernel(const int* __restrict__ src,
                                                   const int* __restrict__ dst,
                                                   const int* __restrict__ rowptr,
                                                   int* __restrict__ cursor,
                                                   int* __restrict__ csr_src) {
    int i = blockIdx.x * blockDim.x + threadIdx.x;
    if (i >= NE) return;
    int d = dst[i];
    int p = atomicAdd(&cursor[d], 1);
    csr_src[rowptr[d] + p] = src[i];
}

// ---------------- fp32 -> bf16 cast ----------------
__global__ __launch_bounds__(256) void cast_kernel(const float* __restrict__ in,
                                                   u16* __restrict__ out, int n4) {
    int i = blockIdx.x * 256 + threadIdx.x;
    if (i >= n4) return;
    float4 v = *(const float4*)(in + (size_t)i * 4);
    ushort4 o;
    o.x = f2bf(v.x); o.y = f2bf(v.y); o.z = f2bf(v.z); o.w = f2bf(v.w);
    *(ushort4*)(out + (size_t)i * 4) = o;
}

// ---------------- fused weight transpose+cast: 9 jobs in one dispatch ----------------
struct WJobs {
    const float* W[9];
    u16* WT[9];
    int K[9];
    int N[9];
};
__global__ __launch_bounds__(256) void wtrans_all(WJobs jobs) {
    int y = blockIdx.y;
    int K = jobs.K[y], N = jobs.N[y];
    int i = blockIdx.x * 256 + threadIdx.x;
    if (i >= K * N) return;
    int k = i / N, n = i % N;
    jobs.WT[y][(size_t)n * K + k] = f2bf(jobs.W[y][i]);
}

// ---------------- CSR mean-aggregate (bf16, 16B loads, sub-edge parallel) ----------------
template <int D>
__global__ __launch_bounds__(256) void aggregate_kernel(const u16* __restrict__ feat,
                                                        const int* __restrict__ csr_src,
                                                        const int* __restrict__ rowptr,
                                                        u16* __restrict__ out) {
    int node = blockIdx.x * 4 + (threadIdx.x >> 6);
    if (node >= NN) return;
    int lane = threadIdx.x & 63;
    int beg = rowptr[node], end = rowptr[node + 1];
    int cnt = end - beg;
    float inv = 1.0f / (float)(cnt > 0 ? cnt : 1);

    constexpr int NSUB = (D == 256) ? 2 : 4;
    constexpr int LPG = 64 / NSUB;
    int sub = lane / LPG;
    int c8 = lane % LPG;

    float a[8] = {0.f, 0.f, 0.f, 0.f, 0.f, 0.f, 0.f, 0.f};
    for (int e = beg + sub; e < end; e += NSUB) {
        int s = csr_src[e];
        bf16x8 u = *(const bf16x8*)(feat + (size_t)s * D + c8 * 8);
#pragma unroll
        for (int j = 0; j < 8; j++) a[j] += bf2f((u16)u[j]);
    }
#pragma unroll
    for (int j = 0; j < 8; j++) {
        if (NSUB == 4) a[j] += __shfl_xor(a[j], 16);
        a[j] += __shfl_xor(a[j], 32);
    }
    if (sub == 0) {
        bf16x8 o;
#pragma unroll
        for (int j = 0; j < 8; j++) o[j] = (short)f2bf(a[j] * inv);
        *(bf16x8*)(out + (size_t)node * D + c8 * 8) = o;
    }
}

// ---------------- bf16 MFMA multi-phase GEMM, full-N per wave ----------------
// Wave computes 16 rows x N cols (N = NT*16). acc += A0@B0 + A1@B1; then
// optional (+bias, relu); then optional phase2 acc += A2@B2; epilogue +bias2.
// mfma_f32_16x16x32_bf16 (m89-verified): A/B frag idx=lane&15, k=(lane>>4)*8+j;
// C/D: col=lane&15, row=(lane>>4)*4+reg.
template <int NT, int RELU01, int PH2, int SPLIT, int OUT_F32>
__global__ __launch_bounds__(256) void gemm_v2(const u16* __restrict__ A0,
                                               const u16* __restrict__ B0T, int K0,
                                               const u16* __restrict__ A1,
                                               const u16* __restrict__ B1T, int K1,
                                               const u16* __restrict__ A2,
                                               const u16* __restrict__ B2T, int K2,
                                               const float* __restrict__ bias,
                                               const float* __restrict__ bias2,
                                               void* __restrict__ Cout, void* __restrict__ Cout2,
                                               int M) {
    constexpr int N = NT * 16;
    int t = threadIdx.x;
    int w = t >> 6, l = t & 63;
    int l15 = l & 15, lhi = l >> 4;
    int rowBase = blockIdx.x * 64 + w * 16;
    int arow = min(rowBase + l15, M - 1);   // clamp: garbage finite, store-guarded

    f32x4 acc[NT];
#pragma unroll
    for (int nt = 0; nt < NT; nt++) acc[nt] = f32x4{0.f, 0.f, 0.f, 0.f};

    {
        const u16* ap = A0 + (size_t)arow * K0 + lhi * 8;
        for (int k0 = 0; k0 < K0; k0 += 32) {
            bf16x8 af = *(const bf16x8*)(ap + k0);
#pragma unroll
            for (int nt = 0; nt < NT; nt++) {
                bf16x8 bfr = *(const bf16x8*)(B0T + (size_t)(nt * 16 + l15) * K0 + k0 + lhi * 8);
                acc[nt] = __builtin_amdgcn_mfma_f32_16x16x32_bf16(af, bfr, acc[nt], 0, 0, 0);
            }
        }
    }
    {
        const u16* ap = A1 + (size_t)arow * K1 + lhi * 8;
        for (int k0 = 0; k0 < K1; k0 += 32) {
            bf16x8 af = *(const bf16x8*)(ap + k0);
#pragma unroll
            for (int nt = 0; nt < NT; nt++) {
                bf16x8 bfr = *(const bf16x8*)(B1T + (size_t)(nt * 16 + l15) * K1 + k0 + lhi * 8);
                acc[nt] = __builtin_amdgcn_mfma_f32_16x16x32_bf16(af, bfr, acc[nt], 0, 0, 0);
            }
        }
    }

    if constexpr (RELU01) {
#pragma unroll
        for (int nt = 0; nt < NT; nt++) {
            float b = bias[nt * 16 + l15];
#pragma unroll
            for (int r = 0; r < 4; r++) acc[nt][r] = fmaxf(acc[nt][r] + b, 0.f);
        }
    }

    if constexpr (PH2) {
        const u16* ap = A2 + (size_t)arow * K2 + lhi * 8;
        for (int k0 = 0; k0 < K2; k0 += 32) {
            bf16x8 af = *(const bf16x8*)(ap + k0);
#pragma unroll
            for (int nt = 0; nt < NT; nt++) {
                bf16x8 bfr = *(const bf16x8*)(B2T + (size_t)(nt * 16 + l15) * K2 + k0 + lhi * 8);
                acc[nt] = __builtin_amdgcn_mfma_f32_16x16x32_bf16(af, bfr, acc[nt], 0, 0, 0);
            }
        }
    }

#pragma unroll
    for (int nt = 0; nt < NT; nt++) {
        int c = nt * 16 + l15;
        float add;
        if constexpr (SPLIT)        add = (c < 64) ? bias[c] : bias2[c - 64];
        else if constexpr (PH2)     add = bias2[c];
        else if constexpr (RELU01)  add = 0.f;
        else                        add = bias[c];
#pragma unroll
        for (int reg = 0; reg < 4; reg++) {
            int r = rowBase + lhi * 4 + reg;
            if (r >= M) continue;
            float v = acc[nt][reg] + add;
            if constexpr (SPLIT) {
                if (c < 64) ((float*)Cout)[(size_t)r * 64 + c] = v;
                else        ((float*)Cout2)[(size_t)r * 64 + (c - 64)] = v;
            } else if constexpr (OUT_F32) {
                ((float*)Cout)[(size_t)r * N + c] = v;
            } else {
                ((u16*)Cout)[(size_t)r * N + c] = f2bf(v);
            }
        }
    }
}

extern "C" void kernel_launch(void* const* d_in, const int* in_sizes, int n_in,
                              void* d_out, int out_size, void* d_ws, size_t ws_size,
                              hipStream_t stream) {
    const float* x    = (const float*)d_in[0];
    const void*  edges = d_in[1];
    const float* W1l  = (const float*)d_in[2];
    const float* b1   = (const float*)d_in[3];
    const float* W1r  = (const float*)d_in[4];
    const float* W2l  = (const float*)d_in[5];
    const float* b2   = (const float*)d_in[6];
    const float* W2r  = (const float*)d_in[7];
    const float* Wres = (const float*)d_in[8];
    const float* bres = (const float*)d_in[9];
    const float* Wmul = (const float*)d_in[10];
    const float* bmu  = (const float*)d_in[11];
    const float* Wmur = (const float*)d_in[12];
    const float* Wlsl = (const float*)d_in[13];
    const float* bls  = (const float*)d_in[14];
    const float* Wlsr = (const float*)d_in[15];
    float* out = (float*)d_out;

    char* ws = (char*)d_ws;
    size_t off = 0;
    int* flag    = (int*)(ws + off); off += 256;
    int* src     = (int*)(ws + off); off += (size_t)NE * 4;
    int* dst     = (int*)(ws + off); off += (size_t)NE * 4;
    int* csr_src = (int*)(ws + off); off += (size_t)NE * 4;
    int* deg     = (int*)(ws + off); off += (size_t)NN * 4;
    int* rowptr  = (int*)(ws + off); off += (size_t)(NN + 8) * 4;
    int* cursor  = (int*)(ws + off); off += (size_t)NN * 4;
    int* incl    = (int*)(ws + off); off += (size_t)NN * 4;
    int* bsum    = (int*)(ws + off); off += 256 * 4;
    int* boff    = (int*)(ws + off); off += 256 * 4;
    off = (off + 255) & ~(size_t)255;
    u16* xb    = (u16*)(ws + off); off += (size_t)NN * 128 * 2;
    u16* agg1b = (u16*)(ws + off); off += (size_t)NN * 128 * 2;
    u16* h1b   = (u16*)(ws + off); off += (size_t)NN * 256 * 2;
    u16* h2b   = (u16*)(ws + off); off += (size_t)NN * 256 * 2;
    u16* aggb  = (u16*)(ws + off); off += (size_t)NN * 256 * 2;   // agg2, then agg3
    u16* W1lT  = (u16*)(ws + off); off += 128 * 256 * 2;
    u16* W1rT  = (u16*)(ws + off); off += 128 * 256 * 2;
    u16* W2lT  = (u16*)(ws + off); off += 256 * 256 * 2;
    u16* W2rT  = (u16*)(ws + off); off += 256 * 256 * 2;
    u16* WresT = (u16*)(ws + off); off += 128 * 256 * 2;
    u16* WcatL = (u16*)(ws + off); off += 128 * 256 * 2;   // [Wmul | Wlsl]^T : [128][256]
    u16* WcatR = (u16*)(ws + off); off += 128 * 256 * 2;   // [Wmur | Wlsr]^T

    hipMemsetAsync(flag, 0, 4, stream);
    hipMemsetAsync(deg, 0, (size_t)NN * 4, stream);
    hipMemsetAsync(cursor, 0, (size_t)NN * 4, stream);

    const int SB = (NN + 255) / 256;   // 79

    detect_kernel<<<64, 256, 0, stream>>>(edges, flag);
    convert_kernel<<<NE / 256, 256, 0, stream>>>(edges, flag, src, dst, deg);
    scan1_kernel<<<SB, 256, 0, stream>>>(deg, incl, bsum);
    scan2_kernel<<<1, 256, 0, stream>>>(bsum, boff);
    scan3_kernel<<<SB, 256, 0, stream>>>(deg, incl, boff, rowptr);
    fill_kernel<<<NE / 256, 256, 0, stream>>>(src, dst, rowptr, cursor, csr_src);

    cast_kernel<<<(NN * 128 / 4 + 255) / 256, 256, 0, stream>>>(x, xb, NN * 128 / 4);

    WJobs jobs;
    jobs.W[0] = W1l;  jobs.WT[0] = W1lT;            jobs.K[0] = 128; jobs.N[0] = 256;
    jobs.W[1] = W1r;  jobs.WT[1] = W1rT;            jobs.K[1] = 128; jobs.N[1] = 256;
    jobs.W[2] = W2l;  jobs.WT[2] = W2lT;            jobs.K[2] = 256; jobs.N[2] = 256;
    jobs.W[3] = W2r;  jobs.WT[3] = W2rT;            jobs.K[3] = 256; jobs.N[3] = 256;
    jobs.W[4] = Wres; jobs.WT[4] = WresT;           jobs.K[4] = 128; jobs.N[4] = 256;
    jobs.W[5] = Wmul; jobs.WT[5] = WcatL;           jobs.K[5] = 256; jobs.N[5] = 64;
    jobs.W[6] = Wlsl; jobs.WT[6] = WcatL + 64*256;  jobs.K[6] = 256; jobs.N[6] = 64;
    jobs.W[7] = Wmur; jobs.WT[7] = WcatR;           jobs.K[7] = 256; jobs.N[7] = 64;
    jobs.W[8] = Wlsr; jobs.WT[8] = WcatR + 64*256;  jobs.K[8] = 256; jobs.N[8] = 64;
    wtrans_all<<<dim3(256, 9), 256, 0, stream>>>(jobs);

    const int GB = (NN + 63) / 64;   // 313

    // layer 1: h1 = relu(mean(x)@W1l + x@W1r + b1)
    aggregate_kernel<128><<<NN / 4, 256, 0, stream>>>(xb, csr_src, rowptr, agg1b);
    gemm_v2<16, 1, 0, 0, 0><<<GB, 256, 0, stream>>>(agg1b, W1lT, 128, xb, W1rT, 128,
                                                    nullptr, nullptr, 0, b1, nullptr,
                                                    h1b, nullptr, NN);
    // layer 2 (fused residual): h2 = relu(mean(h1)@W2l + h1@W2r + b2) + x@Wres + bres
    aggregate_kernel<256><<<NN / 4, 256, 0, stream>>>(h1b, csr_src, rowptr, aggb);
    gemm_v2<16, 1, 1, 0, 0><<<GB, 256, 0, stream>>>(aggb, W2lT, 256, h1b, W2rT, 256,
                                                    xb, WresT, 128, b2, bres,
                                                    h2b, nullptr, NN);
    // layer 3 (fused mu+logstd): [mu|logstd] = mean(h2)@[Wmul|Wlsl] + h2@[Wmur|Wlsr] + [bmu|bls]
    aggregate_kernel<256><<<NN / 4, 256, 0, stream>>>(h2b, csr_src, rowptr, aggb);
    gemm_v2<8, 0, 0, 1, 1><<<GB, 256, 0, stream>>>(aggb, WcatL, 256, h2b, WcatR, 256,
                                                   nullptr, nullptr, 0, bmu, bls,
                                                   out, out + (size_t)NN * 64, NN);
}

// Round 8
// 243.895 us; speedup vs baseline: 1.2267x; 1.2267x over previous
//
#include <hip/hip_runtime.h>
#include <cstddef>

#define NN 20000
#define NE 320000

typedef short bf16x8 __attribute__((ext_vector_type(8)));
typedef float f32x4 __attribute__((ext_vector_type(4)));
typedef unsigned short u16;

__device__ __forceinline__ float bf2f(u16 u) {
    unsigned x = ((unsigned)u) << 16;
    return __builtin_bit_cast(float, x);
}
__device__ __forceinline__ u16 f2bf(float f) {
    unsigned x = __builtin_bit_cast(unsigned, f);
    x = (x + 0x7fff + ((x >> 16) & 1)) >> 16;   // round-to-nearest-even
    return (u16)x;
}

// ---------------- edge-index layout detection (low-contention) ----------------
__global__ __launch_bounds__(256) void detect_kernel(const void* __restrict__ edges, int* flag) {
    __shared__ int bad;
    if (threadIdx.x == 0) bad = 0;
    __syncthreads();
    int any = 0;
    for (int i = blockIdx.x * 256 + threadIdx.x; i < NE; i += 64 * 256) {
        long long v = ((const long long*)edges)[i];
        if (v < 0 || v >= NN) any = 1;
    }
    if (any) bad = 1;               // benign LDS race: all write 1
    __syncthreads();
    if (threadIdx.x == 0 && bad) atomicOr(flag, 1);
}

__global__ __launch_bounds__(256) void convert_kernel(const void* __restrict__ edges,
                                                      const int* __restrict__ flag,
                                                      int* __restrict__ src, int* __restrict__ dst,
                                                      int* __restrict__ deg) {
    int i = blockIdx.x * blockDim.x + threadIdx.x;
    if (i >= NE) return;
    int s, d;
    if (*flag) {
        s = ((const int*)edges)[i];
        d = ((const int*)edges)[NE + i];
    } else {
        s = (int)((const long long*)edges)[i];
        d = (int)((const long long*)edges)[NE + i];
    }
    src[i] = s;
    dst[i] = d;
    atomicAdd(&deg[d], 1);
}

// ---------------- parallel exclusive scan (3 phases) ----------------
__global__ __launch_bounds__(256) void scan1_kernel(const int* __restrict__ deg,
                                                    int* __restrict__ incl, int* __restrict__ bsum) {
    __shared__ int buf[256];
    int t = threadIdx.x, i = blockIdx.x * 256 + t;
    int v = (i < NN) ? deg[i] : 0;
    buf[t] = v;
    __syncthreads();
    for (int off = 1; off < 256; off <<= 1) {
        int u = (t >= off) ? buf[t - off] : 0;
        __syncthreads();
        buf[t] += u;
        __syncthreads();
    }
    if (i < NN) incl[i] = buf[t];
    if (t == 255) bsum[blockIdx.x] = buf[255];
}

__global__ __launch_bounds__(256) void scan2_kernel(const int* __restrict__ bsum,
                                                    int* __restrict__ boff) {
    __shared__ int buf[256];
    const int nb = (NN + 255) / 256;   // 79
    int t = threadIdx.x;
    int v = (t < nb) ? bsum[t] : 0;
    buf[t] = v;
    __syncthreads();
    for (int off = 1; off < 256; off <<= 1) {
        int u = (t >= off) ? buf[t - off] : 0;
        __syncthreads();
        buf[t] += u;
        __syncthreads();
    }
    if (t < nb) boff[t] = buf[t] - v;   // exclusive
}

__global__ __launch_bounds__(256) void scan3_kernel(const int* __restrict__ deg,
                                                    const int* __restrict__ incl,
                                                    const int* __restrict__ boff,
                                                    int* __restrict__ rowptr) {
    int i = blockIdx.x * 256 + threadIdx.x;
    if (i < NN) rowptr[i] = boff[i >> 8] + incl[i] - deg[i];
    if (i == NN) rowptr[NN] = NE;
}

// ---------------- CSR fill ----------------
__global__ __launch_bounds__(256) void fill_kernel(const int* __restrict__ src,
                                                   const int* __restrict__ dst,
                                                   const int* __restrict__ rowptr,
                                                   int* __restrict__ cursor,
                                                   int* __restrict__ csr_src) {
    int i = blockIdx.x * blockDim.x + threadIdx.x;
    if (i >= NE) return;
    int d = dst[i];
    int p = atomicAdd(&cursor[d], 1);
    csr_src[rowptr[d] + p] = src[i];
}

// ---------------- fp32 -> bf16 cast ----------------
__global__ __launch_bounds__(256) void cast_kernel(const float* __restrict__ in,
                                                   u16* __restrict__ out, int n4) {
    int i = blockIdx.x * 256 + threadIdx.x;
    if (i >= n4) return;
    float4 v = *(const float4*)(in + (size_t)i * 4);
    ushort4 o;
    o.x = f2bf(v.x); o.y = f2bf(v.y); o.z = f2bf(v.z); o.w = f2bf(v.w);
    *(ushort4*)(out + (size_t)i * 4) = o;
}

// ---------------- fused weight transpose+cast: 9 jobs in one dispatch ----------------
struct WJobs {
    const float* W[9];
    u16* WT[9];
    int K[9];
    int N[9];
};
__global__ __launch_bounds__(256) void wtrans_all(WJobs jobs) {
    int y = blockIdx.y;
    int K = jobs.K[y], N = jobs.N[y];
    int i = blockIdx.x * 256 + threadIdx.x;
    if (i >= K * N) return;
    int k = i / N, n = i % N;
    jobs.WT[y][(size_t)n * K + k] = f2bf(jobs.W[y][i]);
}

// ---------------- CSR mean-aggregate (bf16, 16B loads, sub-edge parallel) ----------------
template <int D>
__global__ __launch_bounds__(256) void aggregate_kernel(const u16* __restrict__ feat,
                                                        const int* __restrict__ csr_src,
                                                        const int* __restrict__ rowptr,
                                                        u16* __restrict__ out) {
    int node = blockIdx.x * 4 + (threadIdx.x >> 6);
    if (node >= NN) return;
    int lane = threadIdx.x & 63;
    int beg = rowptr[node], end = rowptr[node + 1];
    int cnt = end - beg;
    float inv = 1.0f / (float)(cnt > 0 ? cnt : 1);

    constexpr int NSUB = (D == 256) ? 2 : 4;
    constexpr int LPG = 64 / NSUB;
    int sub = lane / LPG;
    int c8 = lane % LPG;

    float a[8] = {0.f, 0.f, 0.f, 0.f, 0.f, 0.f, 0.f, 0.f};
    for (int e = beg + sub; e < end; e += NSUB) {
        int s = csr_src[e];
        bf16x8 u = *(const bf16x8*)(feat + (size_t)s * D + c8 * 8);
#pragma unroll
        for (int j = 0; j < 8; j++) a[j] += bf2f((u16)u[j]);
    }
#pragma unroll
    for (int j = 0; j < 8; j++) {
        if (NSUB == 4) a[j] += __shfl_xor(a[j], 16);
        a[j] += __shfl_xor(a[j], 32);
    }
    if (sub == 0) {
        bf16x8 o;
#pragma unroll
        for (int j = 0; j < 8; j++) o[j] = (short)f2bf(a[j] * inv);
        *(bf16x8*)(out + (size_t)node * D + c8 * 8) = o;
    }
}

// ---------------- bf16 MFMA GEMM, B-in-registers, row-streaming ----------------
// Each wave owns one 16-col block; its full B slice (all phases) lives in VGPRs.
// Rows streamed in 16-row blocks: inner loop = A-load + MFMA only.
// acc = A0@B0 + A1@B1 [; +bias,relu] [; += A2@B2] ; epilogue.
// mfma_f32_16x16x32_bf16 (m89-verified): A/B frag idx=lane&15, k=(lane>>4)*8+j;
// C/D: col=lane&15, row=(lane>>4)*4+reg.
// Grid: (NN/RPW, N/64), block = 4 waves. NN % RPW == 0, RPW % 16 == 0.
template <int NK0, int NK1, int NK2, int RELU01, int SPLIT, int OUT_F32, int RPW>
__global__ __launch_bounds__(256) void gemm_v3(const u16* __restrict__ A0,
                                               const u16* __restrict__ B0T,
                                               const u16* __restrict__ A1,
                                               const u16* __restrict__ B1T,
                                               const u16* __restrict__ A2,
                                               const u16* __restrict__ B2T,
                                               const float* __restrict__ bias,
                                               const float* __restrict__ bias2,
                                               void* __restrict__ Cout,
                                               void* __restrict__ Cout2,
                                               int NOUT) {
    constexpr int K0 = NK0 * 32, K1 = NK1 * 32, K2 = NK2 * 32;
    int t = threadIdx.x;
    int w = t >> 6, l = t & 63;
    int l15 = l & 15, lhi = l >> 4;
    int cb = blockIdx.y * 4 + w;        // 16-col block id
    int col = cb * 16 + l15;
    int rowBeg = blockIdx.x * RPW;

    // ---- load full B slice into registers (once) ----
    bf16x8 b0[NK0], b1[NK1];
#pragma unroll
    for (int i = 0; i < NK0; i++)
        b0[i] = *(const bf16x8*)(B0T + (size_t)col * K0 + i * 32 + lhi * 8);
#pragma unroll
    for (int i = 0; i < NK1; i++)
        b1[i] = *(const bf16x8*)(B1T + (size_t)col * K1 + i * 32 + lhi * 8);
    bf16x8 b2[NK2 > 0 ? NK2 : 1];
    if constexpr (NK2 > 0) {
#pragma unroll
        for (int i = 0; i < NK2; i++)
            b2[i] = *(const bf16x8*)(B2T + (size_t)col * K2 + i * 32 + lhi * 8);
    }

    float badd;
    if constexpr (SPLIT)       badd = (col < 64) ? bias[col] : bias2[col - 64];
    else if constexpr (NK2 > 0) badd = bias2[col];   // bres after phase2
    else if constexpr (RELU01) badd = 0.f;           // bias consumed at relu
    else                       badd = bias[col];
    float brelu = RELU01 ? bias[col] : 0.f;

#pragma unroll 1
    for (int rb = 0; rb < RPW / 16; rb++) {
        int arow = rowBeg + rb * 16 + l15;
        f32x4 accA = f32x4{0.f, 0.f, 0.f, 0.f};
        f32x4 accB = f32x4{0.f, 0.f, 0.f, 0.f};

        const u16* ap0 = A0 + (size_t)arow * K0 + lhi * 8;
#pragma unroll
        for (int i = 0; i < NK0; i++) {
            bf16x8 af = *(const bf16x8*)(ap0 + i * 32);
            if (i & 1) accB = __builtin_amdgcn_mfma_f32_16x16x32_bf16(af, b0[i], accB, 0, 0, 0);
            else       accA = __builtin_amdgcn_mfma_f32_16x16x32_bf16(af, b0[i], accA, 0, 0, 0);
        }
        const u16* ap1 = A1 + (size_t)arow * K1 + lhi * 8;
#pragma unroll
        for (int i = 0; i < NK1; i++) {
            bf16x8 af = *(const bf16x8*)(ap1 + i * 32);
            if (i & 1) accB = __builtin_amdgcn_mfma_f32_16x16x32_bf16(af, b1[i], accB, 0, 0, 0);
            else       accA = __builtin_amdgcn_mfma_f32_16x16x32_bf16(af, b1[i], accA, 0, 0, 0);
        }

        if constexpr (RELU01) {
#pragma unroll
            for (int r = 0; r < 4; r++) {
                accA[r] = fmaxf(accA[r] + accB[r] + brelu, 0.f);
                accB[r] = 0.f;
            }
        }

        if constexpr (NK2 > 0) {
            const u16* ap2 = A2 + (size_t)arow * K2 + lhi * 8;
#pragma unroll
            for (int i = 0; i < NK2; i++) {
                bf16x8 af = *(const bf16x8*)(ap2 + i * 32);
                if (i & 1) accB = __builtin_amdgcn_mfma_f32_16x16x32_bf16(af, b2[i], accB, 0, 0, 0);
                else       accA = __builtin_amdgcn_mfma_f32_16x16x32_bf16(af, b2[i], accA, 0, 0, 0);
            }
        }

#pragma unroll
        for (int reg = 0; reg < 4; reg++) {
            int r = rowBeg + rb * 16 + lhi * 4 + reg;
            float v = accA[reg] + accB[reg] + badd;
            if constexpr (SPLIT) {
                if (col < 64) ((float*)Cout)[(size_t)r * 64 + col] = v;
                else          ((float*)Cout2)[(size_t)r * 64 + (col - 64)] = v;
            } else if constexpr (OUT_F32) {
                ((float*)Cout)[(size_t)r * NOUT + col] = v;
            } else {
                ((u16*)Cout)[(size_t)r * NOUT + col] = f2bf(v);
            }
        }
    }
}

extern "C" void kernel_launch(void* const* d_in, const int* in_sizes, int n_in,
                              void* d_out, int out_size, void* d_ws, size_t ws_size,
                              hipStream_t stream) {
    const float* x    = (const float*)d_in[0];
    const void*  edges = d_in[1];
    const float* W1l  = (const float*)d_in[2];
    const float* b1   = (const float*)d_in[3];
    const float* W1r  = (const float*)d_in[4];
    const float* W2l  = (const float*)d_in[5];
    const float* b2   = (const float*)d_in[6];
    const float* W2r  = (const float*)d_in[7];
    const float* Wres = (const float*)d_in[8];
    const float* bres = (const float*)d_in[9];
    const float* Wmul = (const float*)d_in[10];
    const float* bmu  = (const float*)d_in[11];
    const float* Wmur = (const float*)d_in[12];
    const float* Wlsl = (const float*)d_in[13];
    const float* bls  = (const float*)d_in[14];
    const float* Wlsr = (const float*)d_in[15];
    float* out = (float*)d_out;

    char* ws = (char*)d_ws;
    size_t off = 0;
    int* flag    = (int*)(ws + off); off += 256;
    int* src     = (int*)(ws + off); off += (size_t)NE * 4;
    int* dst     = (int*)(ws + off); off += (size_t)NE * 4;
    int* csr_src = (int*)(ws + off); off += (size_t)NE * 4;
    int* deg     = (int*)(ws + off); off += (size_t)NN * 4;
    int* rowptr  = (int*)(ws + off); off += (size_t)(NN + 8) * 4;
    int* cursor  = (int*)(ws + off); off += (size_t)NN * 4;
    int* incl    = (int*)(ws + off); off += (size_t)NN * 4;
    int* bsum    = (int*)(ws + off); off += 256 * 4;
    int* boff    = (int*)(ws + off); off += 256 * 4;
    off = (off + 255) & ~(size_t)255;
    u16* xb    = (u16*)(ws + off); off += (size_t)NN * 128 * 2;
    u16* agg1b = (u16*)(ws + off); off += (size_t)NN * 128 * 2;
    u16* h1b   = (u16*)(ws + off); off += (size_t)NN * 256 * 2;
    u16* h2b   = (u16*)(ws + off); off += (size_t)NN * 256 * 2;
    u16* aggb  = (u16*)(ws + off); off += (size_t)NN * 256 * 2;   // agg2, then agg3
    u16* W1lT  = (u16*)(ws + off); off += 128 * 256 * 2;
    u16* W1rT  = (u16*)(ws + off); off += 128 * 256 * 2;
    u16* W2lT  = (u16*)(ws + off); off += 256 * 256 * 2;
    u16* W2rT  = (u16*)(ws + off); off += 256 * 256 * 2;
    u16* WresT = (u16*)(ws + off); off += 128 * 256 * 2;
    u16* WcatL = (u16*)(ws + off); off += 128 * 256 * 2;   // [Wmul | Wlsl]^T : [128][256]
    u16* WcatR = (u16*)(ws + off); off += 128 * 256 * 2;   // [Wmur | Wlsr]^T

    hipMemsetAsync(flag, 0, 4, stream);
    hipMemsetAsync(deg, 0, (size_t)NN * 4, stream);
    hipMemsetAsync(cursor, 0, (size_t)NN * 4, stream);

    const int SB = (NN + 255) / 256;   // 79

    detect_kernel<<<64, 256, 0, stream>>>(edges, flag);
    convert_kernel<<<NE / 256, 256, 0, stream>>>(edges, flag, src, dst, deg);
    scan1_kernel<<<SB, 256, 0, stream>>>(deg, incl, bsum);
    scan2_kernel<<<1, 256, 0, stream>>>(bsum, boff);
    scan3_kernel<<<SB, 256, 0, stream>>>(deg, incl, boff, rowptr);
    fill_kernel<<<NE / 256, 256, 0, stream>>>(src, dst, rowptr, cursor, csr_src);

    cast_kernel<<<(NN * 128 / 4 + 255) / 256, 256, 0, stream>>>(x, xb, NN * 128 / 4);

    WJobs jobs;
    jobs.W[0] = W1l;  jobs.WT[0] = W1lT;            jobs.K[0] = 128; jobs.N[0] = 256;
    jobs.W[1] = W1r;  jobs.WT[1] = W1rT;            jobs.K[1] = 128; jobs.N[1] = 256;
    jobs.W[2] = W2l;  jobs.WT[2] = W2lT;            jobs.K[2] = 256; jobs.N[2] = 256;
    jobs.W[3] = W2r;  jobs.WT[3] = W2rT;            jobs.K[3] = 256; jobs.N[3] = 256;
    jobs.W[4] = Wres; jobs.WT[4] = WresT;           jobs.K[4] = 128; jobs.N[4] = 256;
    jobs.W[5] = Wmul; jobs.WT[5] = WcatL;           jobs.K[5] = 256; jobs.N[5] = 64;
    jobs.W[6] = Wlsl; jobs.WT[6] = WcatL + 64*256;  jobs.K[6] = 256; jobs.N[6] = 64;
    jobs.W[7] = Wmur; jobs.WT[7] = WcatR;           jobs.K[7] = 256; jobs.N[7] = 64;
    jobs.W[8] = Wlsr; jobs.WT[8] = WcatR + 64*256;  jobs.K[8] = 256; jobs.N[8] = 64;
    wtrans_all<<<dim3(256, 9), 256, 0, stream>>>(jobs);

    const int RPW = 80;                 // rows per wave; NN/RPW = 250 exactly
    const int RC = NN / RPW;            // 250

    // layer 1: h1 = relu(mean(x)@W1l + x@W1r + b1)
    aggregate_kernel<128><<<NN / 4, 256, 0, stream>>>(xb, csr_src, rowptr, agg1b);
    gemm_v3<4, 4, 0, 1, 0, 0, 80><<<dim3(RC, 4), 256, 0, stream>>>(
        agg1b, W1lT, xb, W1rT, nullptr, nullptr, b1, nullptr, h1b, nullptr, 256);

    // layer 2 (fused residual): h2 = relu(mean(h1)@W2l + h1@W2r + b2) + x@Wres + bres
    aggregate_kernel<256><<<NN / 4, 256, 0, stream>>>(h1b, csr_src, rowptr, aggb);
    gemm_v3<8, 8, 4, 1, 0, 0, 80><<<dim3(RC, 4), 256, 0, stream>>>(
        aggb, W2lT, h1b, W2rT, xb, WresT, b2, bres, h2b, nullptr, 256);

    // layer 3 (fused mu+logstd): [mu|logstd] = mean(h2)@[Wmul|Wlsl] + h2@[Wmur|Wlsr] + [bmu|bls]
    aggregate_kernel<256><<<NN / 4, 256, 0, stream>>>(h2b, csr_src, rowptr, aggb);
    gemm_v3<8, 8, 0, 0, 1, 1, 80><<<dim3(RC, 2), 256, 0, stream>>>(
        aggb, WcatL, h2b, WcatR, nullptr, nullptr, bmu, bls, out, out + (size_t)NN * 64, 128);
}